// Round 24
// baseline (115.231 us; speedup 1.0000x reference)
//
#include <hip/hip_runtime.h>
#include <hip/hip_bf16.h>

#define IN_DIM   27000
#define ENC_DIM  768
#define LATENT   128
#define K_CODES  512
#define BATCH    256
#define NWC      211            // k_enc blocks = ceil(27000/128)
#define BN_R     128
#define NRB      211            // k_recon blocks = ceil(27000/128)
#define PADK     40             // LDS k-pitch (ushorts)
#define PADK2    72             // LDS k-pitch for 2-tile (BK=64) buffers
#define PADW     136            // LDS k-pitch for Wc tile (128 + 8)
#define NKT      24             // ENC_DIM/32
#define NCH      211            // zpart chunks (210 in d_out + 1 in ws)

// ---- d_out-region scratch (inside x_recon area, 6,912,000 f32 slots) ----
#define OUT_ZPART_F   0         // [210][256][128] = 6,881,280 slots <= 6,912,000

// ---- d_ws layout (f32 slots), ~989 KB ----
#define WS_Z      0                          // (unused; kept for layout)
#define WS_QUANT  (WS_Z + BATCH*LATENT)      // (unused; kept for layout)
#define WS_IDX    (WS_QUANT + BATCH*LATENT)  // int[256]
#define WS_VQPART (WS_IDX + BATCH)           // f32[256]
#define WS_RECON  (WS_VQPART + BATCH)        // f32[NRB] (reserve 1024)
#define WS_HBF    (WS_RECON + 1024)          // ushort[16][24][64][8] fragment layout
#define WS_WLH    (WS_HBF + 49152)           // ushort[128][768] hi (n-major)
#define WS_WLL    (WS_WLH + 49152)           // ushort[128][768] lo
#define WS_ZLAST  (WS_WLL + 49152)           // f32[256][128] (zpart chunk 210)

typedef unsigned short ushort_t;
typedef __attribute__((ext_vector_type(4))) float f32x4;
typedef __attribute__((ext_vector_type(8))) short short8x;
typedef __attribute__((ext_vector_type(4))) short short4x;

__device__ __forceinline__ ushort_t bf16_rne(float f) {
    unsigned u = __float_as_uint(f);
    unsigned r = 0x7FFFu + ((u >> 16) & 1u);
    return (ushort_t)((u + r) >> 16);
}
// truncate-hi + rne-lo split: |v - (hi+lo)| <= 2^-17 |v|
__device__ __forceinline__ void split_f32(float v, ushort_t& h, ushort_t& l) {
    unsigned u  = __float_as_uint(v);
    unsigned uh = u & 0xFFFF0000u;
    h = (ushort_t)(uh >> 16);
    l = bf16_rne(v - __uint_as_float(uh));
}
// Barrier that waits only on LDS ops: global loads (private VGPR dests) stay
// in flight across it.
__device__ __forceinline__ void lds_barrier() {
    asm volatile("s_waitcnt lgkmcnt(0)\n\ts_barrier" ::: "memory");
}

// ============ Kernel 0: pre-split W_lat -> n-major bf16 hi/lo ============
__global__ __launch_bounds__(256) void k_prep(const float* __restrict__ Wlat,
                                              ushort_t* __restrict__ wlh,
                                              ushort_t* __restrict__ wll) {
    const int i4 = blockIdx.x * 256 + threadIdx.x;   // 0..24575
    const int k  = i4 >> 5;                          // 0..767
    const int n4 = (i4 & 31) * 4;
    float4 v = *(const float4*)(Wlat + (size_t)k * LATENT + n4);
    float vv[4] = {v.x, v.y, v.z, v.w};
#pragma unroll
    for (int j = 0; j < 4; j++) {
        ushort_t h, l;
        split_f32(vv[j], h, l);
        wlh[(size_t)(n4 + j) * ENC_DIM + k] = h;
        wll[(size_t)(n4 + j) * ENC_DIM + k] = l;
    }
}

// ============ Kernel 1: FUSED encoder (r21-proven shape) ============
// Phase 1: Wc tile [128 k-rows][128 lat] via BK=64 dbuf pipeline, wave 16x128.
// Epilogue: Wc tile -> LDS (aliased). Phase 2: zpart_c = x[:,kslice] @ Wc_tile.
__global__ __launch_bounds__(512) void k_enc(const float* __restrict__ Wenc,
                                             const ushort_t* __restrict__ wlh,
                                             const ushort_t* __restrict__ wll,
                                             const float* __restrict__ x,
                                             float* __restrict__ zpart,
                                             float* __restrict__ zlast) {
    __shared__ ushort_t Bh[2][128][PADK2], Bl[2][128][PADK2];  // 73,728 B
    ushort_t* WcHi = &Bh[0][0][0];   // [128 lat][PADW k]
    ushort_t* WcLo = &Bl[0][0][0];
    const int t = threadIdx.x, lane = t & 63, wid = t >> 6;    // 8 waves
    const int lrow = lane & 15, kg = lane >> 4;
    const int half = wid >> 2, w8 = wid & 3;
    const int m0 = blockIdx.x * 128;
    int arow = m0 + half * 64 + w8 * 16 + lrow; if (arow > IN_DIM - 1) arow = IN_DIM - 1;
    const float* aptr = Wenc + (size_t)arow * ENC_DIM + kg * 8;
    const int bn = t >> 2, bkc = (t & 3) * 16;     // B stage: 16 ushorts/side/pair
    const size_t bbase = (size_t)bn * ENC_DIM + bkc;

    f32x4 acc[8];
#pragma unroll
    for (int ni = 0; ni < 8; ni++) acc[ni] = (f32x4){0.f, 0.f, 0.f, 0.f};

    float av0[8], av1[8], av2[8], av3[8];
    short8x bhA[2], blA[2], bhB[2], blB[2];

#define WC_ALOAD(S, kt)                                                         \
    {                                                                           \
        *(float4*)&av##S[0] = *(const float4*)(aptr + (kt) * 32);               \
        *(float4*)&av##S[4] = *(const float4*)(aptr + (kt) * 32 + 4);           \
    }
#define WC_BLOADP(SET, kt0)                                                     \
    {                                                                           \
        const ushort_t* ph = wlh + bbase + (kt0) * 32;                          \
        const ushort_t* pl = wll + bbase + (kt0) * 32;                          \
        bh##SET[0] = *(const short8x*)ph;  bh##SET[1] = *(const short8x*)(ph + 8); \
        bl##SET[0] = *(const short8x*)pl;  bl##SET[1] = *(const short8x*)(pl + 8); \
    }
#define WC_BSTOREP(SET, BI)                                                     \
    {                                                                           \
        *(short8x*)&Bh[BI][bn][bkc]     = bh##SET[0];                           \
        *(short8x*)&Bh[BI][bn][bkc + 8] = bh##SET[1];                           \
        *(short8x*)&Bl[BI][bn][bkc]     = bl##SET[0];                           \
        *(short8x*)&Bl[BI][bn][bkc + 8] = bl##SET[1];                           \
    }
#define WC_MFMAT(S, BI, SUB)                                                    \
    {                                                                           \
        short8x ah, al;                                                         \
        _Pragma("unroll")                                                       \
        for (int i = 0; i < 8; i++) {                                           \
            ushort_t h, l; split_f32(av##S[i], h, l);                           \
            ah[i] = (short)h; al[i] = (short)l;                                 \
        }                                                                       \
        __builtin_amdgcn_s_setprio(1);                                          \
        _Pragma("unroll")                                                       \
        for (int ni = 0; ni < 8; ni++) {                                        \
            short8x bhf = *(const short8x*)&Bh[BI][ni * 16 + lrow][(SUB) * 32 + kg * 8]; \
            short8x blf = *(const short8x*)&Bl[BI][ni * 16 + lrow][(SUB) * 32 + kg * 8]; \
            acc[ni] = __builtin_amdgcn_mfma_f32_16x16x32_bf16(ah, bhf, acc[ni], 0, 0, 0); \
            acc[ni] = __builtin_amdgcn_mfma_f32_16x16x32_bf16(ah, blf, acc[ni], 0, 0, 0); \
            acc[ni] = __builtin_amdgcn_mfma_f32_16x16x32_bf16(al, bhf, acc[ni], 0, 0, 0); \
        }                                                                       \
        __builtin_amdgcn_s_setprio(0);                                          \
    }

    // Prologue: buf0 <- tiles 0,1 (via setB); setA <- tiles 2,3; av0,av1 <- tiles 0,1.
    WC_ALOAD(0, 0) WC_ALOAD(1, 1)
    WC_BLOADP(B, 0)
    WC_BSTOREP(B, 0)
    WC_BLOADP(A, 2)
    lds_barrier();

    for (int j = 0; j < NKT / 4; j++) {               // 6 iters, 2 intervals each
        const int kt0 = 4 * j;
        if (kt0 + 2 < NKT) { WC_ALOAD(2, kt0 + 2) WC_ALOAD(3, kt0 + 3) }
        if (kt0 + 4 < NKT) WC_BLOADP(B, kt0 + 4)
        WC_MFMAT(0, 0, 0)
        WC_MFMAT(1, 0, 1)
        if (kt0 + 2 < NKT) WC_BSTOREP(A, 1)
        lds_barrier();
        if (kt0 + 4 < NKT) { WC_ALOAD(0, kt0 + 4) WC_ALOAD(1, kt0 + 5) }
        if (kt0 + 6 < NKT) WC_BLOADP(A, kt0 + 6)
        if (kt0 + 2 < NKT) { WC_MFMAT(2, 1, 0) WC_MFMAT(3, 1, 1) }
        if (kt0 + 4 < NKT) WC_BSTOREP(B, 0)
        lds_barrier();
    }
#undef WC_ALOAD
#undef WC_BLOADP
#undef WC_BSTOREP
#undef WC_MFMAT

    // ---- Phase-2 x prefetch (issue before epilogue; independent of LDS) ----
    const float* xp0 = x + (size_t)(wid * 32 + lrow) * IN_DIM + m0;
    const float* xp1 = xp0 + (size_t)16 * IN_DIM;
    float axvX[16], axvY[16];
#define ZXLOAD(SET, kt2)                                                        \
    {                                                                           \
        const int kloc = (kt2) * 32 + kg * 8;                                   \
        if (m0 + kloc < IN_DIM) {                                               \
            *(float4*)&axv##SET[0]  = *(const float4*)(xp0 + kloc);             \
            *(float4*)&axv##SET[4]  = *(const float4*)(xp0 + kloc + 4);         \
            *(float4*)&axv##SET[8]  = *(const float4*)(xp1 + kloc);             \
            *(float4*)&axv##SET[12] = *(const float4*)(xp1 + kloc + 4);         \
        } else {                                                                \
            _Pragma("unroll")                                                   \
            for (int i = 0; i < 16; i++) axv##SET[i] = 0.f;                     \
        }                                                                       \
    }
    ZXLOAD(X, 0)
    ZXLOAD(Y, 1)

    // ---- Epilogue: Wc tile -> LDS (aliased; all phase-1 reads drained) ----
    {
        const int rowk = half * 64 + w8 * 16 + kg * 4;   // local k-row base (mult of 4)
#pragma unroll
        for (int ni = 0; ni < 8; ni++) {
            const int col = ni * 16 + lrow;              // lat
            short4x h4, l4;
#pragma unroll
            for (int r = 0; r < 4; r++) {
                ushort_t h, l; split_f32(acc[ni][r], h, l);
                h4[r] = (short)h; l4[r] = (short)l;
            }
            *(short4x*)&WcHi[(size_t)col * PADW + rowk] = h4;
            *(short4x*)&WcLo[(size_t)col * PADW + rowk] = l4;
        }
    }
    lds_barrier();

    // ---- Phase 2: zpart_c = x[:,kslice] @ Wc_tile ----
    f32x4 acc2[2][8];
#pragma unroll
    for (int mi = 0; mi < 2; mi++)
#pragma unroll
        for (int ni = 0; ni < 8; ni++) acc2[mi][ni] = (f32x4){0.f, 0.f, 0.f, 0.f};

#define ZMFMA(SET, kt2)                                                         \
    {                                                                           \
        short8x ah0, al0, ah1, al1;                                             \
        _Pragma("unroll")                                                       \
        for (int i = 0; i < 8; i++) {                                           \
            ushort_t h, l;                                                      \
            split_f32(axv##SET[i], h, l);     ah0[i] = (short)h; al0[i] = (short)l; \
            split_f32(axv##SET[8 + i], h, l); ah1[i] = (short)h; al1[i] = (short)l; \
        }                                                                       \
        __builtin_amdgcn_s_setprio(1);                                          \
        _Pragma("unroll")                                                       \
        for (int ni = 0; ni < 8; ni++) {                                        \
            const size_t bo = (size_t)(ni * 16 + lrow) * PADW + (kt2) * 32 + kg * 8; \
            short8x bhf = *(const short8x*)&WcHi[bo];                           \
            short8x blf = *(const short8x*)&WcLo[bo];                           \
            acc2[0][ni] = __builtin_amdgcn_mfma_f32_16x16x32_bf16(ah0, bhf, acc2[0][ni], 0, 0, 0); \
            acc2[0][ni] = __builtin_amdgcn_mfma_f32_16x16x32_bf16(ah0, blf, acc2[0][ni], 0, 0, 0); \
            acc2[0][ni] = __builtin_amdgcn_mfma_f32_16x16x32_bf16(al0, bhf, acc2[0][ni], 0, 0, 0); \
            acc2[1][ni] = __builtin_amdgcn_mfma_f32_16x16x32_bf16(ah1, bhf, acc2[1][ni], 0, 0, 0); \
            acc2[1][ni] = __builtin_amdgcn_mfma_f32_16x16x32_bf16(ah1, blf, acc2[1][ni], 0, 0, 0); \
            acc2[1][ni] = __builtin_amdgcn_mfma_f32_16x16x32_bf16(al1, bhf, acc2[1][ni], 0, 0, 0); \
        }                                                                       \
        __builtin_amdgcn_s_setprio(0);                                          \
    }

    ZMFMA(X, 0)
    ZXLOAD(X, 2)
    ZMFMA(Y, 1)
    ZXLOAD(Y, 3)
    ZMFMA(X, 2)
    ZMFMA(Y, 3)
#undef ZXLOAD
#undef ZMFMA

    // ---- zpart write (k_z-proven epilogue mapping) ----
    float* zp = (blockIdx.x == NCH - 1) ? zlast
                                        : zpart + (size_t)blockIdx.x * (BATCH * LATENT);
#pragma unroll
    for (int mi = 0; mi < 2; mi++) {
        const int rowb = wid * 32 + mi * 16 + kg * 4;    // batch row base
#pragma unroll
        for (int ni = 0; ni < 8; ni++) {
            const int col = ni * 16 + lrow;              // lat
#pragma unroll
            for (int r = 0; r < 4; r++)
                zp[(size_t)(rowb + r) * LATENT + col] = acc2[mi][ni][r];
        }
    }
}

// ============ Kernel 2: VQ fused with z-reduction AND h-row compute ============
// Threads t<128: z[b][t] = blat[t] + sum_c zpart[c][b][t] + zlast[b][t]
// (identical order to old k_zred). VQ argmin as before. Then block b computes
// h row b = relu(qs @ Wd1 + bd1) directly into hfrag (same math as old k_h).
__global__ __launch_bounds__(256) void k_vq(const float* __restrict__ zpart,
                                            const float* __restrict__ zlast,
                                            const float* __restrict__ blat,
                                            const float* __restrict__ cb,
                                            const float* __restrict__ Wd1,
                                            const float* __restrict__ bd1,
                                            ushort_t* __restrict__ hfrag,
                                            int* __restrict__ idx_out,
                                            float* __restrict__ vqpart) {
    __shared__ float zs[LATENT];
    __shared__ float qs[LATENT];
    __shared__ float ds_[256];
    __shared__ int   is_[256];
    const int b = blockIdx.x, t = threadIdx.x;
    if (t < LATENT) {
        float s = blat[t];
        const float* zp = zpart + (size_t)b * LATENT + t;
        for (int c = 0; c < NCH - 1; c++)
            s += zp[(size_t)c * (BATCH * LATENT)];
        s += zlast[(size_t)b * LATENT + t];
        zs[t] = s;
    }
    __syncthreads();

    float best_d = 3.4e38f; int best_i = 0;
#pragma unroll
    for (int rep = 0; rep < 2; rep++) {
        const int k = t + rep * 256;
        const float* e = cb + (size_t)k * LATENT;
        float acc = 0.f;
#pragma unroll 4
        for (int d = 0; d < LATENT; d += 4) {
            float4 ev = *(const float4*)(e + d);
            float d0 = zs[d]   - ev.x;
            float d1 = zs[d+1] - ev.y;
            float d2 = zs[d+2] - ev.z;
            float d3 = zs[d+3] - ev.w;
            acc += d0*d0 + d1*d1 + d2*d2 + d3*d3;
        }
        if (acc < best_d) { best_d = acc; best_i = k; }
    }
    ds_[t] = best_d; is_[t] = best_i;
    __syncthreads();
    for (int s = 128; s > 0; s >>= 1) {
        if (t < s) {
            float od = ds_[t+s]; int oi = is_[t+s];
            if (od < ds_[t] || (od == ds_[t] && oi < is_[t])) { ds_[t] = od; is_[t] = oi; }
        }
        __syncthreads();
    }
    const int best = is_[0];
    if (t == 0) idx_out[b] = best;

    // Stage quant row in LDS (replaces global quant buffer).
    if (t < LATENT) qs[t] = cb[(size_t)best * LATENT + t];
    __syncthreads();

    // vq partial (identical arithmetic to before)
    float sq = 0.f;
    if (t < LATENT) {
        float dd = qs[t] - zs[t];
        sq = dd * dd;
    }
    ds_[t] = sq;
    __syncthreads();
    for (int s = 128; s > 0; s >>= 1) {
        if (t < s) ds_[t] += ds_[t+s];
        __syncthreads();
    }
    if (t == 0) vqpart[b] = ds_[0];

    // h row b: each thread computes cols t, t+256, t+512 (identical fmaf
    // chain to old k_h), writes hfrag fragment slots directly.
    const int mt = b >> 4, lrow2 = b & 15;
#pragma unroll
    for (int p = 0; p < 3; p++) {
        const int col = t + p * 256;
        float acc = bd1[col];
#pragma unroll 8
        for (int k = 0; k < LATENT; k++)
            acc = fmaf(qs[k], Wd1[(size_t)k * ENC_DIM + col], acc);
        const int kt = col >> 5, kg2 = (col & 31) >> 3, j = col & 7;
        hfrag[((size_t)(mt * NKT + kt) * 64 + kg2 * 16 + lrow2) * 8 + j] =
            bf16_rne(fmaxf(acc, 0.f));
    }
}

// ============ Kernel 3: x_recon = h @ W_d2 + b_d2 + fused loss ============
__global__ __launch_bounds__(512) void k_recon_mfma(const ushort_t* __restrict__ hfrag,
                                                    const float* __restrict__ Wd2,
                                                    const float* __restrict__ bd2,
                                                    const float* __restrict__ x,
                                                    float* __restrict__ out,
                                                    float* __restrict__ reconpart) {
    __shared__ ushort_t Bts[2][BN_R][PADK];   // 20480 B
    __shared__ float red[512];
    const int t = threadIdx.x, lane = t & 63, wid = t >> 6;   // wid 0..7
    const int lrow = lane & 15, kg = lane >> 4;
    const int n0 = blockIdx.x * BN_R;

    const int b_n   = t & 127;
    const int b_kq  = t >> 7;
    const bool bvalid = (n0 + b_n) < IN_DIM;
    const ushort_t* afrag0 = hfrag + ((size_t)(wid * 2 + 0) * NKT * 64 + lane) * 8;
    const ushort_t* afrag1 = hfrag + ((size_t)(wid * 2 + 1) * NKT * 64 + lane) * 8;

    f32x4 acc[2][8];
#pragma unroll
    for (int mi = 0; mi < 2; mi++)
#pragma unroll
        for (int ni = 0; ni < 8; ni++) acc[mi][ni] = (f32x4){0.f, 0.f, 0.f, 0.f};

    short8x a0[2], a1[2], a2[2], a3[2];
    float   bregs0[8], bregs1[8], bregs2[8], bregs3[8];

#define R_ALOAD(S, kt)                                                          \
    {                                                                           \
        a##S[0] = *(const short8x*)(afrag0 + (size_t)(kt) * 512);               \
        a##S[1] = *(const short8x*)(afrag1 + (size_t)(kt) * 512);               \
    }
#define R_BLOAD(S, kt)                                                          \
    {                                                                           \
        if (bvalid) {                                                           \
            const float* wp = Wd2 + (size_t)((kt) * 32 + b_kq * 8) * IN_DIM + n0 + b_n; \
            _Pragma("unroll")                                                   \
            for (int j = 0; j < 8; j++) bregs##S[j] = wp[(size_t)j * IN_DIM];   \
        } else {                                                                \
            _Pragma("unroll")                                                   \
            for (int j = 0; j < 8; j++) bregs##S[j] = 0.f;                      \
        }                                                                       \
    }
#define R_BSTORE(S, BI)                                                         \
    {                                                                           \
        short8x bb;                                                             \
        _Pragma("unroll")                                                       \
        for (int j = 0; j < 8; j++) bb[j] = (short)bf16_rne(bregs##S[j]);       \
        *(short8x*)&Bts[BI][b_n][b_kq * 8] = bb;                                \
    }
#define R_MFMA(S, BI)                                                           \
    {                                                                           \
        __builtin_amdgcn_s_setprio(1);                                          \
        _Pragma("unroll")                                                       \
        for (int ni = 0; ni < 8; ni++) {                                        \
            short8x b_ = *(const short8x*)&Bts[BI][ni * 16 + lrow][kg * 8];     \
            acc[0][ni] = __builtin_amdgcn_mfma_f32_16x16x32_bf16(a##S[0], b_, acc[0][ni], 0, 0, 0); \
            acc[1][ni] = __builtin_amdgcn_mfma_f32_16x16x32_bf16(a##S[1], b_, acc[1][ni], 0, 0, 0); \
        }                                                                       \
        __builtin_amdgcn_s_setprio(0);                                          \
    }

    R_ALOAD(0, 0) R_BLOAD(0, 0)
    R_ALOAD(1, 1) R_BLOAD(1, 1)
    R_ALOAD(2, 2) R_BLOAD(2, 2)
    R_BSTORE(0, 0)
    lds_barrier();

    for (int kt0 = 0; kt0 < NKT; kt0 += 4) {
        if (kt0 + 3 < NKT) { R_ALOAD(3, kt0 + 3) R_BLOAD(3, kt0 + 3) }
        R_MFMA(0, 0)
        if (kt0 + 1 < NKT) R_BSTORE(1, 1)
        lds_barrier();
        if (kt0 + 4 < NKT) { R_ALOAD(0, kt0 + 4) R_BLOAD(0, kt0 + 4) }
        R_MFMA(1, 1)
        if (kt0 + 2 < NKT) R_BSTORE(2, 0)
        lds_barrier();
        if (kt0 + 5 < NKT) { R_ALOAD(1, kt0 + 5) R_BLOAD(1, kt0 + 5) }
        R_MFMA(2, 0)
        if (kt0 + 3 < NKT) R_BSTORE(3, 1)
        lds_barrier();
        if (kt0 + 6 < NKT) { R_ALOAD(2, kt0 + 6) R_BLOAD(2, kt0 + 6) }
        R_MFMA(3, 1)
        if (kt0 + 4 < NKT) R_BSTORE(0, 0)
        lds_barrier();
    }
#undef R_ALOAD
#undef R_BLOAD
#undef R_BSTORE
#undef R_MFMA

    float lsq = 0.f;
#pragma unroll
    for (int mi = 0; mi < 2; mi++) {
        const int rowb = wid * 32 + mi * 16 + kg * 4;
#pragma unroll
        for (int ni = 0; ni < 8; ni++) {
            const int col = n0 + ni * 16 + lrow;
            if (col < IN_DIM) {
                const float bb = bd2[col];
#pragma unroll
                for (int r = 0; r < 4; r++) {
                    const int row = rowb + r;
                    float v = acc[mi][ni][r] + bb;
                    float e = v - x[(size_t)row * IN_DIM + col];
                    lsq += e * e;
                    out[(size_t)row * IN_DIM + col] = v;
                }
            }
        }
    }

    red[t] = lsq;
    __syncthreads();
    for (int s = 256; s > 0; s >>= 1) {
        if (t < s) red[t] += red[t + s];
        __syncthreads();
    }
    if (t == 0) reconpart[blockIdx.x] = red[0];
}

// ============ Kernel 4: finalize losses + indices (f32) ============
__global__ __launch_bounds__(256) void k_final(const float* __restrict__ reconpart,
                                               const float* __restrict__ vqpart,
                                               const int* __restrict__ idx,
                                               float* __restrict__ out,
                                               long long obase) {
    __shared__ float red[256];
    const int t = threadIdx.x;
    float s = 0.f;
    for (int i = t; i < NRB; i += 256) s += reconpart[i];
    red[t] = s;
    __syncthreads();
    for (int st = 128; st > 0; st >>= 1) {
        if (t < st) red[t] += red[t + st];
        __syncthreads();
    }
    const float recon_sum = red[0];
    __syncthreads();
    red[t] = vqpart[t];
    __syncthreads();
    for (int st = 128; st > 0; st >>= 1) {
        if (t < st) red[t] += red[t + st];
        __syncthreads();
    }
    const float vq_sum = red[0];
    if (t == 0) {
        float recon_loss = recon_sum / (float)((size_t)BATCH * IN_DIM);
        float vq_loss = 1.1f * vq_sum / (float)(BATCH * LATENT);
        out[obase + 0] = recon_loss + vq_loss;
        out[obase + 1] = vq_loss;
    }
    out[obase + 2 + t] = (float)idx[t];
}

extern "C" void kernel_launch(void* const* d_in, const int* in_sizes, int n_in,
                              void* d_out, int out_size, void* d_ws, size_t ws_size,
                              hipStream_t stream) {
    int ix = 0, iwe = 1, iwl = 2, ibl = 3, icb = 4, iwd1 = 5, ibd1 = 6, iwd2 = 7, ibd2 = 8;
    if (n_in == 9 && in_sizes[0] != BATCH * IN_DIM) {
        int p20[2] = {1, 7}, n20 = 0, p98[2] = {2, 5}, n98 = 0;
        for (int i = 0; i < 9; i++) {
            const int s = in_sizes[i];
            if      (s == BATCH * IN_DIM)    ix = i;
            else if (s == LATENT)            ibl = i;
            else if (s == K_CODES * LATENT)  icb = i;
            else if (s == ENC_DIM)           ibd1 = i;
            else if (s == IN_DIM)            ibd2 = i;
            else if (s == IN_DIM * ENC_DIM)  { if (n20 < 2) p20[n20++] = i; }
            else if (s == ENC_DIM * LATENT)  { if (n98 < 2) p98[n98++] = i; }
        }
        iwd2 = p20[0]; iwe = p20[1];
        iwd1 = p98[0]; iwl = p98[1];
    }
    const float* x    = (const float*)d_in[ix];
    const float* Wenc = (const float*)d_in[iwe];
    const float* Wlat = (const float*)d_in[iwl];
    const float* blat = (const float*)d_in[ibl];
    const float* cb   = (const float*)d_in[icb];
    const float* Wd1  = (const float*)d_in[iwd1];
    const float* bd1  = (const float*)d_in[ibd1];
    const float* Wd2  = (const float*)d_in[iwd2];
    const float* bd2  = (const float*)d_in[ibd2];

    float* out   = (float*)d_out;
    float* zpart = out + OUT_ZPART_F;

    float* ws            = (float*)d_ws;
    int*   idxp          = (int*)(ws + WS_IDX);
    float* vqpart        = ws + WS_VQPART;
    float* reconpart     = ws + WS_RECON;
    ushort_t* hfrag      = (ushort_t*)(ws + WS_HBF);
    ushort_t* wlh        = (ushort_t*)(ws + WS_WLH);
    ushort_t* wll        = (ushort_t*)(ws + WS_WLL);
    float* zlast         = ws + WS_ZLAST;

    const long long obase = (long long)out_size - 258;

    k_prep      <<<96, 256, 0, stream>>>(Wlat, wlh, wll);
    k_enc       <<<NWC, 512, 0, stream>>>(Wenc, wlh, wll, x, zpart, zlast);
    k_vq        <<<BATCH, 256, 0, stream>>>(zpart, zlast, blat, cb, Wd1, bd1,
                                            hfrag, idxp, vqpart);
    k_recon_mfma<<<NRB, 512, 0, stream>>>(hfrag, Wd2, bd2, x, out, reconpart);
    k_final     <<<1, 256, 0, stream>>>(reconpart, vqpart, idxp, out, obase);
}

// Round 25
// 104.752 us; speedup vs baseline: 1.1000x; 1.1000x over previous
//
#include <hip/hip_runtime.h>
#include <hip/hip_bf16.h>

#define IN_DIM   27000
#define ENC_DIM  768
#define LATENT   128
#define K_CODES  512
#define BATCH    256
#define NWC      211            // k_enc blocks = ceil(27000/128)
#define BN_R     128
#define NRB      211            // k_recon blocks = ceil(27000/128)
#define PADK     40             // LDS k-pitch (ushorts)
#define PADK2    72             // LDS k-pitch for 2-tile (BK=64) buffers
#define PADW     136            // LDS k-pitch for Wc tile (128 + 8)
#define NKT      24             // ENC_DIM/32
#define NCH      211            // zpart chunks (210 in d_out + 1 in ws)

// ---- d_out-region scratch (inside x_recon area, 6,912,000 f32 slots) ----
#define OUT_ZPART_F   0         // [210][256][128] = 6,881,280 slots <= 6,912,000

// ---- d_ws layout (f32 slots), ~989 KB ----
#define WS_Z      0                          // (unused; kept for layout)
#define WS_QUANT  (WS_Z + BATCH*LATENT)      // (unused; kept for layout)
#define WS_IDX    (WS_QUANT + BATCH*LATENT)  // int[256]
#define WS_VQPART (WS_IDX + BATCH)           // f32[256]
#define WS_RECON  (WS_VQPART + BATCH)        // f32[NRB] (reserve 1024)
#define WS_HBF    (WS_RECON + 1024)          // ushort[16][24][64][8] fragment layout
#define WS_WLH    (WS_HBF + 49152)           // ushort[128][768] hi (n-major)
#define WS_WLL    (WS_WLH + 49152)           // ushort[128][768] lo
#define WS_ZLAST  (WS_WLL + 49152)           // f32[256][128] (zpart chunk 210)

typedef unsigned short ushort_t;
typedef __attribute__((ext_vector_type(4))) float f32x4;
typedef __attribute__((ext_vector_type(8))) short short8x;
typedef __attribute__((ext_vector_type(4))) short short4x;

__device__ __forceinline__ ushort_t bf16_rne(float f) {
    unsigned u = __float_as_uint(f);
    unsigned r = 0x7FFFu + ((u >> 16) & 1u);
    return (ushort_t)((u + r) >> 16);
}
// truncate-hi + rne-lo split: |v - (hi+lo)| <= 2^-17 |v|
__device__ __forceinline__ void split_f32(float v, ushort_t& h, ushort_t& l) {
    unsigned u  = __float_as_uint(v);
    unsigned uh = u & 0xFFFF0000u;
    h = (ushort_t)(uh >> 16);
    l = bf16_rne(v - __uint_as_float(uh));
}
// Barrier that waits only on LDS ops: global loads (private VGPR dests) stay
// in flight across it.
__device__ __forceinline__ void lds_barrier() {
    asm volatile("s_waitcnt lgkmcnt(0)\n\ts_barrier" ::: "memory");
}

// ============ Kernel 0: pre-split W_lat -> n-major bf16 hi/lo ============
__global__ __launch_bounds__(256) void k_prep(const float* __restrict__ Wlat,
                                              ushort_t* __restrict__ wlh,
                                              ushort_t* __restrict__ wll) {
    const int i4 = blockIdx.x * 256 + threadIdx.x;   // 0..24575
    const int k  = i4 >> 5;                          // 0..767
    const int n4 = (i4 & 31) * 4;
    float4 v = *(const float4*)(Wlat + (size_t)k * LATENT + n4);
    float vv[4] = {v.x, v.y, v.z, v.w};
#pragma unroll
    for (int j = 0; j < 4; j++) {
        ushort_t h, l;
        split_f32(vv[j], h, l);
        wlh[(size_t)(n4 + j) * ENC_DIM + k] = h;
        wll[(size_t)(n4 + j) * ENC_DIM + k] = l;
    }
}

// ============ Kernel 1: FUSED encoder (r21-proven shape) ============
// Phase 1: Wc tile [128 k-rows][128 lat] via BK=64 dbuf pipeline, wave 16x128.
// Epilogue: Wc tile -> LDS (aliased). Phase 2: zpart_c = x[:,kslice] @ Wc_tile.
__global__ __launch_bounds__(512) void k_enc(const float* __restrict__ Wenc,
                                             const ushort_t* __restrict__ wlh,
                                             const ushort_t* __restrict__ wll,
                                             const float* __restrict__ x,
                                             float* __restrict__ zpart,
                                             float* __restrict__ zlast) {
    __shared__ ushort_t Bh[2][128][PADK2], Bl[2][128][PADK2];  // 73,728 B
    ushort_t* WcHi = &Bh[0][0][0];   // [128 lat][PADW k]
    ushort_t* WcLo = &Bl[0][0][0];
    const int t = threadIdx.x, lane = t & 63, wid = t >> 6;    // 8 waves
    const int lrow = lane & 15, kg = lane >> 4;
    const int half = wid >> 2, w8 = wid & 3;
    const int m0 = blockIdx.x * 128;
    int arow = m0 + half * 64 + w8 * 16 + lrow; if (arow > IN_DIM - 1) arow = IN_DIM - 1;
    const float* aptr = Wenc + (size_t)arow * ENC_DIM + kg * 8;
    const int bn = t >> 2, bkc = (t & 3) * 16;     // B stage: 16 ushorts/side/pair
    const size_t bbase = (size_t)bn * ENC_DIM + bkc;

    f32x4 acc[8];
#pragma unroll
    for (int ni = 0; ni < 8; ni++) acc[ni] = (f32x4){0.f, 0.f, 0.f, 0.f};

    float av0[8], av1[8], av2[8], av3[8];
    short8x bhA[2], blA[2], bhB[2], blB[2];

#define WC_ALOAD(S, kt)                                                         \
    {                                                                           \
        *(float4*)&av##S[0] = *(const float4*)(aptr + (kt) * 32);               \
        *(float4*)&av##S[4] = *(const float4*)(aptr + (kt) * 32 + 4);           \
    }
#define WC_BLOADP(SET, kt0)                                                     \
    {                                                                           \
        const ushort_t* ph = wlh + bbase + (kt0) * 32;                          \
        const ushort_t* pl = wll + bbase + (kt0) * 32;                          \
        bh##SET[0] = *(const short8x*)ph;  bh##SET[1] = *(const short8x*)(ph + 8); \
        bl##SET[0] = *(const short8x*)pl;  bl##SET[1] = *(const short8x*)(pl + 8); \
    }
#define WC_BSTOREP(SET, BI)                                                     \
    {                                                                           \
        *(short8x*)&Bh[BI][bn][bkc]     = bh##SET[0];                           \
        *(short8x*)&Bh[BI][bn][bkc + 8] = bh##SET[1];                           \
        *(short8x*)&Bl[BI][bn][bkc]     = bl##SET[0];                           \
        *(short8x*)&Bl[BI][bn][bkc + 8] = bl##SET[1];                           \
    }
#define WC_MFMAT(S, BI, SUB)                                                    \
    {                                                                           \
        short8x ah, al;                                                         \
        _Pragma("unroll")                                                       \
        for (int i = 0; i < 8; i++) {                                           \
            ushort_t h, l; split_f32(av##S[i], h, l);                           \
            ah[i] = (short)h; al[i] = (short)l;                                 \
        }                                                                       \
        __builtin_amdgcn_s_setprio(1);                                          \
        _Pragma("unroll")                                                       \
        for (int ni = 0; ni < 8; ni++) {                                        \
            short8x bhf = *(const short8x*)&Bh[BI][ni * 16 + lrow][(SUB) * 32 + kg * 8]; \
            short8x blf = *(const short8x*)&Bl[BI][ni * 16 + lrow][(SUB) * 32 + kg * 8]; \
            acc[ni] = __builtin_amdgcn_mfma_f32_16x16x32_bf16(ah, bhf, acc[ni], 0, 0, 0); \
            acc[ni] = __builtin_amdgcn_mfma_f32_16x16x32_bf16(ah, blf, acc[ni], 0, 0, 0); \
            acc[ni] = __builtin_amdgcn_mfma_f32_16x16x32_bf16(al, bhf, acc[ni], 0, 0, 0); \
        }                                                                       \
        __builtin_amdgcn_s_setprio(0);                                          \
    }

    // Prologue: buf0 <- tiles 0,1 (via setB); setA <- tiles 2,3; av0,av1 <- tiles 0,1.
    WC_ALOAD(0, 0) WC_ALOAD(1, 1)
    WC_BLOADP(B, 0)
    WC_BSTOREP(B, 0)
    WC_BLOADP(A, 2)
    lds_barrier();

    for (int j = 0; j < NKT / 4; j++) {               // 6 iters, 2 intervals each
        const int kt0 = 4 * j;
        if (kt0 + 2 < NKT) { WC_ALOAD(2, kt0 + 2) WC_ALOAD(3, kt0 + 3) }
        if (kt0 + 4 < NKT) WC_BLOADP(B, kt0 + 4)
        WC_MFMAT(0, 0, 0)
        WC_MFMAT(1, 0, 1)
        if (kt0 + 2 < NKT) WC_BSTOREP(A, 1)
        lds_barrier();
        if (kt0 + 4 < NKT) { WC_ALOAD(0, kt0 + 4) WC_ALOAD(1, kt0 + 5) }
        if (kt0 + 6 < NKT) WC_BLOADP(A, kt0 + 6)
        if (kt0 + 2 < NKT) { WC_MFMAT(2, 1, 0) WC_MFMAT(3, 1, 1) }
        if (kt0 + 4 < NKT) WC_BSTOREP(B, 0)
        lds_barrier();
    }
#undef WC_ALOAD
#undef WC_BLOADP
#undef WC_BSTOREP
#undef WC_MFMAT

    // ---- Phase-2 x prefetch (issue before epilogue; independent of LDS) ----
    const float* xp0 = x + (size_t)(wid * 32 + lrow) * IN_DIM + m0;
    const float* xp1 = xp0 + (size_t)16 * IN_DIM;
    float axvX[16], axvY[16];
#define ZXLOAD(SET, kt2)                                                        \
    {                                                                           \
        const int kloc = (kt2) * 32 + kg * 8;                                   \
        if (m0 + kloc < IN_DIM) {                                               \
            *(float4*)&axv##SET[0]  = *(const float4*)(xp0 + kloc);             \
            *(float4*)&axv##SET[4]  = *(const float4*)(xp0 + kloc + 4);         \
            *(float4*)&axv##SET[8]  = *(const float4*)(xp1 + kloc);             \
            *(float4*)&axv##SET[12] = *(const float4*)(xp1 + kloc + 4);         \
        } else {                                                                \
            _Pragma("unroll")                                                   \
            for (int i = 0; i < 16; i++) axv##SET[i] = 0.f;                     \
        }                                                                       \
    }
    ZXLOAD(X, 0)
    ZXLOAD(Y, 1)

    // ---- Epilogue: Wc tile -> LDS (aliased; all phase-1 reads drained) ----
    {
        const int rowk = half * 64 + w8 * 16 + kg * 4;   // local k-row base (mult of 4)
#pragma unroll
        for (int ni = 0; ni < 8; ni++) {
            const int col = ni * 16 + lrow;              // lat
            short4x h4, l4;
#pragma unroll
            for (int r = 0; r < 4; r++) {
                ushort_t h, l; split_f32(acc[ni][r], h, l);
                h4[r] = (short)h; l4[r] = (short)l;
            }
            *(short4x*)&WcHi[(size_t)col * PADW + rowk] = h4;
            *(short4x*)&WcLo[(size_t)col * PADW + rowk] = l4;
        }
    }
    lds_barrier();

    // ---- Phase 2: zpart_c = x[:,kslice] @ Wc_tile ----
    f32x4 acc2[2][8];
#pragma unroll
    for (int mi = 0; mi < 2; mi++)
#pragma unroll
        for (int ni = 0; ni < 8; ni++) acc2[mi][ni] = (f32x4){0.f, 0.f, 0.f, 0.f};

#define ZMFMA(SET, kt2)                                                         \
    {                                                                           \
        short8x ah0, al0, ah1, al1;                                             \
        _Pragma("unroll")                                                       \
        for (int i = 0; i < 8; i++) {                                           \
            ushort_t h, l;                                                      \
            split_f32(axv##SET[i], h, l);     ah0[i] = (short)h; al0[i] = (short)l; \
            split_f32(axv##SET[8 + i], h, l); ah1[i] = (short)h; al1[i] = (short)l; \
        }                                                                       \
        __builtin_amdgcn_s_setprio(1);                                          \
        _Pragma("unroll")                                                       \
        for (int ni = 0; ni < 8; ni++) {                                        \
            const size_t bo = (size_t)(ni * 16 + lrow) * PADW + (kt2) * 32 + kg * 8; \
            short8x bhf = *(const short8x*)&WcHi[bo];                           \
            short8x blf = *(const short8x*)&WcLo[bo];                           \
            acc2[0][ni] = __builtin_amdgcn_mfma_f32_16x16x32_bf16(ah0, bhf, acc2[0][ni], 0, 0, 0); \
            acc2[0][ni] = __builtin_amdgcn_mfma_f32_16x16x32_bf16(ah0, blf, acc2[0][ni], 0, 0, 0); \
            acc2[0][ni] = __builtin_amdgcn_mfma_f32_16x16x32_bf16(al0, bhf, acc2[0][ni], 0, 0, 0); \
            acc2[1][ni] = __builtin_amdgcn_mfma_f32_16x16x32_bf16(ah1, bhf, acc2[1][ni], 0, 0, 0); \
            acc2[1][ni] = __builtin_amdgcn_mfma_f32_16x16x32_bf16(ah1, blf, acc2[1][ni], 0, 0, 0); \
            acc2[1][ni] = __builtin_amdgcn_mfma_f32_16x16x32_bf16(al1, blf, acc2[1][ni], 0, 0, 0); \
        }                                                                       \
        __builtin_amdgcn_s_setprio(0);                                          \
    }
#undef ZMFMA

#define ZMFMA(SET, kt2)                                                         \
    {                                                                           \
        short8x ah0, al0, ah1, al1;                                             \
        _Pragma("unroll")                                                       \
        for (int i = 0; i < 8; i++) {                                           \
            ushort_t h, l;                                                      \
            split_f32(axv##SET[i], h, l);     ah0[i] = (short)h; al0[i] = (short)l; \
            split_f32(axv##SET[8 + i], h, l); ah1[i] = (short)h; al1[i] = (short)l; \
        }                                                                       \
        __builtin_amdgcn_s_setprio(1);                                          \
        _Pragma("unroll")                                                       \
        for (int ni = 0; ni < 8; ni++) {                                        \
            const size_t bo = (size_t)(ni * 16 + lrow) * PADW + (kt2) * 32 + kg * 8; \
            short8x bhf = *(const short8x*)&WcHi[bo];                           \
            short8x blf = *(const short8x*)&WcLo[bo];                           \
            acc2[0][ni] = __builtin_amdgcn_mfma_f32_16x16x32_bf16(ah0, bhf, acc2[0][ni], 0, 0, 0); \
            acc2[0][ni] = __builtin_amdgcn_mfma_f32_16x16x32_bf16(ah0, blf, acc2[0][ni], 0, 0, 0); \
            acc2[0][ni] = __builtin_amdgcn_mfma_f32_16x16x32_bf16(al0, bhf, acc2[0][ni], 0, 0, 0); \
            acc2[1][ni] = __builtin_amdgcn_mfma_f32_16x16x32_bf16(ah1, bhf, acc2[1][ni], 0, 0, 0); \
            acc2[1][ni] = __builtin_amdgcn_mfma_f32_16x16x32_bf16(ah1, blf, acc2[1][ni], 0, 0, 0); \
            acc2[1][ni] = __builtin_amdgcn_mfma_f32_16x16x32_bf16(al1, bhf, acc2[1][ni], 0, 0, 0); \
        }                                                                       \
        __builtin_amdgcn_s_setprio(0);                                          \
    }

    ZMFMA(X, 0)
    ZXLOAD(X, 2)
    ZMFMA(Y, 1)
    ZXLOAD(Y, 3)
    ZMFMA(X, 2)
    ZMFMA(Y, 3)
#undef ZXLOAD
#undef ZMFMA

    // ---- zpart write (k_z-proven epilogue mapping) ----
    float* zp = (blockIdx.x == NCH - 1) ? zlast
                                        : zpart + (size_t)blockIdx.x * (BATCH * LATENT);
#pragma unroll
    for (int mi = 0; mi < 2; mi++) {
        const int rowb = wid * 32 + mi * 16 + kg * 4;    // batch row base
#pragma unroll
        for (int ni = 0; ni < 8; ni++) {
            const int col = ni * 16 + lrow;              // lat
#pragma unroll
            for (int r = 0; r < 4; r++)
                zp[(size_t)(rowb + r) * LATENT + col] = acc2[mi][ni][r];
        }
    }
}

// ============ Kernel 2: VQ fused with z-reduction ============
// Threads t<128 compute z[b][t] = blat[t] + sum_c zpart[c][b][t] + zlast[b][t]
// (identical summation order to the old k_zred), then VQ as before.
__global__ __launch_bounds__(256) void k_vq(const float* __restrict__ zpart,
                                            const float* __restrict__ zlast,
                                            const float* __restrict__ blat,
                                            const float* __restrict__ cb,
                                            float* __restrict__ quant,
                                            int* __restrict__ idx_out,
                                            float* __restrict__ vqpart) {
    __shared__ float zs[LATENT];
    __shared__ float ds_[256];
    __shared__ int   is_[256];
    const int b = blockIdx.x, t = threadIdx.x;
    if (t < LATENT) {
        float s = blat[t];
        const float* zp = zpart + (size_t)b * LATENT + t;
        for (int c = 0; c < NCH - 1; c++)
            s += zp[(size_t)c * (BATCH * LATENT)];
        s += zlast[(size_t)b * LATENT + t];
        zs[t] = s;
    }
    __syncthreads();

    float best_d = 3.4e38f; int best_i = 0;
#pragma unroll
    for (int rep = 0; rep < 2; rep++) {
        const int k = t + rep * 256;
        const float* e = cb + (size_t)k * LATENT;
        float acc = 0.f;
#pragma unroll 4
        for (int d = 0; d < LATENT; d += 4) {
            float4 ev = *(const float4*)(e + d);
            float d0 = zs[d]   - ev.x;
            float d1 = zs[d+1] - ev.y;
            float d2 = zs[d+2] - ev.z;
            float d3 = zs[d+3] - ev.w;
            acc += d0*d0 + d1*d1 + d2*d2 + d3*d3;
        }
        if (acc < best_d) { best_d = acc; best_i = k; }
    }
    ds_[t] = best_d; is_[t] = best_i;
    __syncthreads();
    for (int s = 128; s > 0; s >>= 1) {
        if (t < s) {
            float od = ds_[t+s]; int oi = is_[t+s];
            if (od < ds_[t] || (od == ds_[t] && oi < is_[t])) { ds_[t] = od; is_[t] = oi; }
        }
        __syncthreads();
    }
    const int best = is_[0];
    if (t == 0) idx_out[b] = best;

    float sq = 0.f;
    if (t < LATENT) {
        float q = cb[(size_t)best * LATENT + t];
        quant[b * LATENT + t] = q;
        float dd = q - zs[t];
        sq = dd * dd;
    }
    __syncthreads();
    ds_[t] = sq;
    __syncthreads();
    for (int s = 128; s > 0; s >>= 1) {
        if (t < s) ds_[t] += ds_[t+s];
        __syncthreads();
    }
    if (t == 0) vqpart[b] = ds_[0];
}

// ============ Kernel 3: h = relu(quant @ W_d1 + b_d1) -> bf16 FRAGMENT layout ============
__global__ __launch_bounds__(256) void k_h(const float* __restrict__ quant,
                                           const float* __restrict__ Wd1,
                                           const float* __restrict__ bd1,
                                           ushort_t* __restrict__ hfrag) {
    const int bid = blockIdx.x, t = threadIdx.x;
    const int row = bid / 3;
    const int col = (bid % 3) * 256 + t;
    float acc = bd1[col];
    const float* q = quant + row * LATENT;
#pragma unroll 8
    for (int k = 0; k < LATENT; k++)
        acc = fmaf(q[k], Wd1[(size_t)k * ENC_DIM + col], acc);
    const int mt = row >> 4, lrow = row & 15;
    const int kt = col >> 5, kg = (col & 31) >> 3, j = col & 7;
    hfrag[((size_t)(mt * NKT + kt) * 64 + kg * 16 + lrow) * 8 + j] =
        bf16_rne(fmaxf(acc, 0.f));
}

// ============ Kernel 4: x_recon = h @ W_d2 + b_d2 + fused loss ============
__global__ __launch_bounds__(512) void k_recon_mfma(const ushort_t* __restrict__ hfrag,
                                                    const float* __restrict__ Wd2,
                                                    const float* __restrict__ bd2,
                                                    const float* __restrict__ x,
                                                    float* __restrict__ out,
                                                    float* __restrict__ reconpart) {
    __shared__ ushort_t Bts[2][BN_R][PADK];   // 20480 B
    __shared__ float red[512];
    const int t = threadIdx.x, lane = t & 63, wid = t >> 6;   // wid 0..7
    const int lrow = lane & 15, kg = lane >> 4;
    const int n0 = blockIdx.x * BN_R;

    const int b_n   = t & 127;
    const int b_kq  = t >> 7;
    const bool bvalid = (n0 + b_n) < IN_DIM;
    const ushort_t* afrag0 = hfrag + ((size_t)(wid * 2 + 0) * NKT * 64 + lane) * 8;
    const ushort_t* afrag1 = hfrag + ((size_t)(wid * 2 + 1) * NKT * 64 + lane) * 8;

    f32x4 acc[2][8];
#pragma unroll
    for (int mi = 0; mi < 2; mi++)
#pragma unroll
        for (int ni = 0; ni < 8; ni++) acc[mi][ni] = (f32x4){0.f, 0.f, 0.f, 0.f};

    short8x a0[2], a1[2], a2[2], a3[2];
    float   bregs0[8], bregs1[8], bregs2[8], bregs3[8];

#define R_ALOAD(S, kt)                                                          \
    {                                                                           \
        a##S[0] = *(const short8x*)(afrag0 + (size_t)(kt) * 512);               \
        a##S[1] = *(const short8x*)(afrag1 + (size_t)(kt) * 512);               \
    }
#define R_BLOAD(S, kt)                                                          \
    {                                                                           \
        if (bvalid) {                                                           \
            const float* wp = Wd2 + (size_t)((kt) * 32 + b_kq * 8) * IN_DIM + n0 + b_n; \
            _Pragma("unroll")                                                   \
            for (int j = 0; j < 8; j++) bregs##S[j] = wp[(size_t)j * IN_DIM];   \
        } else {                                                                \
            _Pragma("unroll")                                                   \
            for (int j = 0; j < 8; j++) bregs##S[j] = 0.f;                      \
        }                                                                       \
    }
#define R_BSTORE(S, BI)                                                         \
    {                                                                           \
        short8x bb;                                                             \
        _Pragma("unroll")                                                       \
        for (int j = 0; j < 8; j++) bb[j] = (short)bf16_rne(bregs##S[j]);       \
        *(short8x*)&Bts[BI][b_n][b_kq * 8] = bb;                                \
    }
#define R_MFMA(S, BI)                                                           \
    {                                                                           \
        __builtin_amdgcn_s_setprio(1);                                          \
        _Pragma("unroll")                                                       \
        for (int ni = 0; ni < 8; ni++) {                                        \
            short8x b_ = *(const short8x*)&Bts[BI][ni * 16 + lrow][kg * 8];     \
            acc[0][ni] = __builtin_amdgcn_mfma_f32_16x16x32_bf16(a##S[0], b_, acc[0][ni], 0, 0, 0); \
            acc[1][ni] = __builtin_amdgcn_mfma_f32_16x16x32_bf16(a##S[1], b_, acc[1][ni], 0, 0, 0); \
        }                                                                       \
        __builtin_amdgcn_s_setprio(0);                                          \
    }

    R_ALOAD(0, 0) R_BLOAD(0, 0)
    R_ALOAD(1, 1) R_BLOAD(1, 1)
    R_ALOAD(2, 2) R_BLOAD(2, 2)
    R_BSTORE(0, 0)
    lds_barrier();

    for (int kt0 = 0; kt0 < NKT; kt0 += 4) {
        if (kt0 + 3 < NKT) { R_ALOAD(3, kt0 + 3) R_BLOAD(3, kt0 + 3) }
        R_MFMA(0, 0)
        if (kt0 + 1 < NKT) R_BSTORE(1, 1)
        lds_barrier();
        if (kt0 + 4 < NKT) { R_ALOAD(0, kt0 + 4) R_BLOAD(0, kt0 + 4) }
        R_MFMA(1, 1)
        if (kt0 + 2 < NKT) R_BSTORE(2, 0)
        lds_barrier();
        if (kt0 + 5 < NKT) { R_ALOAD(1, kt0 + 5) R_BLOAD(1, kt0 + 5) }
        R_MFMA(2, 0)
        if (kt0 + 3 < NKT) R_BSTORE(3, 1)
        lds_barrier();
        if (kt0 + 6 < NKT) { R_ALOAD(2, kt0 + 6) R_BLOAD(2, kt0 + 6) }
        R_MFMA(3, 1)
        if (kt0 + 4 < NKT) R_BSTORE(0, 0)
        lds_barrier();
    }
#undef R_ALOAD
#undef R_BLOAD
#undef R_BSTORE
#undef R_MFMA

    float lsq = 0.f;
#pragma unroll
    for (int mi = 0; mi < 2; mi++) {
        const int rowb = wid * 32 + mi * 16 + kg * 4;
#pragma unroll
        for (int ni = 0; ni < 8; ni++) {
            const int col = n0 + ni * 16 + lrow;
            if (col < IN_DIM) {
                const float bb = bd2[col];
#pragma unroll
                for (int r = 0; r < 4; r++) {
                    const int row = rowb + r;
                    float v = acc[mi][ni][r] + bb;
                    float e = v - x[(size_t)row * IN_DIM + col];
                    lsq += e * e;
                    out[(size_t)row * IN_DIM + col] = v;
                }
            }
        }
    }

    red[t] = lsq;
    __syncthreads();
    for (int s = 256; s > 0; s >>= 1) {
        if (t < s) red[t] += red[t + s];
        __syncthreads();
    }
    if (t == 0) reconpart[blockIdx.x] = red[0];
}

// ============ Kernel 5: finalize losses + indices (f32) ============
__global__ __launch_bounds__(256) void k_final(const float* __restrict__ reconpart,
                                               const float* __restrict__ vqpart,
                                               const int* __restrict__ idx,
                                               float* __restrict__ out,
                                               long long obase) {
    __shared__ float red[256];
    const int t = threadIdx.x;
    float s = 0.f;
    for (int i = t; i < NRB; i += 256) s += reconpart[i];
    red[t] = s;
    __syncthreads();
    for (int st = 128; st > 0; st >>= 1) {
        if (t < st) red[t] += red[t + st];
        __syncthreads();
    }
    const float recon_sum = red[0];
    __syncthreads();
    red[t] = vqpart[t];
    __syncthreads();
    for (int st = 128; st > 0; st >>= 1) {
        if (t < st) red[t] += red[t + st];
        __syncthreads();
    }
    const float vq_sum = red[0];
    if (t == 0) {
        float recon_loss = recon_sum / (float)((size_t)BATCH * IN_DIM);
        float vq_loss = 1.1f * vq_sum / (float)(BATCH * LATENT);
        out[obase + 0] = recon_loss + vq_loss;
        out[obase + 1] = vq_loss;
    }
    out[obase + 2 + t] = (float)idx[t];
}

extern "C" void kernel_launch(void* const* d_in, const int* in_sizes, int n_in,
                              void* d_out, int out_size, void* d_ws, size_t ws_size,
                              hipStream_t stream) {
    int ix = 0, iwe = 1, iwl = 2, ibl = 3, icb = 4, iwd1 = 5, ibd1 = 6, iwd2 = 7, ibd2 = 8;
    if (n_in == 9 && in_sizes[0] != BATCH * IN_DIM) {
        int p20[2] = {1, 7}, n20 = 0, p98[2] = {2, 5}, n98 = 0;
        for (int i = 0; i < 9; i++) {
            const int s = in_sizes[i];
            if      (s == BATCH * IN_DIM)    ix = i;
            else if (s == LATENT)            ibl = i;
            else if (s == K_CODES * LATENT)  icb = i;
            else if (s == ENC_DIM)           ibd1 = i;
            else if (s == IN_DIM)            ibd2 = i;
            else if (s == IN_DIM * ENC_DIM)  { if (n20 < 2) p20[n20++] = i; }
            else if (s == ENC_DIM * LATENT)  { if (n98 < 2) p98[n98++] = i; }
        }
        iwd2 = p20[0]; iwe = p20[1];
        iwd1 = p98[0]; iwl = p98[1];
    }
    const float* x    = (const float*)d_in[ix];
    const float* Wenc = (const float*)d_in[iwe];
    const float* Wlat = (const float*)d_in[iwl];
    const float* blat = (const float*)d_in[ibl];
    const float* cb   = (const float*)d_in[icb];
    const float* Wd1  = (const float*)d_in[iwd1];
    const float* bd1  = (const float*)d_in[ibd1];
    const float* Wd2  = (const float*)d_in[iwd2];
    const float* bd2  = (const float*)d_in[ibd2];

    float* out   = (float*)d_out;
    float* zpart = out + OUT_ZPART_F;

    float* ws            = (float*)d_ws;
    float* quant         = ws + WS_QUANT;
    int*   idxp          = (int*)(ws + WS_IDX);
    float* vqpart        = ws + WS_VQPART;
    float* reconpart     = ws + WS_RECON;
    ushort_t* hfrag      = (ushort_t*)(ws + WS_HBF);
    ushort_t* wlh        = (ushort_t*)(ws + WS_WLH);
    ushort_t* wll        = (ushort_t*)(ws + WS_WLL);
    float* zlast         = ws + WS_ZLAST;

    const long long obase = (long long)out_size - 258;

    k_prep      <<<96, 256, 0, stream>>>(Wlat, wlh, wll);
    k_enc       <<<NWC, 512, 0, stream>>>(Wenc, wlh, wll, x, zpart, zlast);
    k_vq        <<<BATCH, 256, 0, stream>>>(zpart, zlast, blat, cb, quant, idxp, vqpart);
    k_h         <<<768, 256, 0, stream>>>(quant, Wd1, bd1, hfrag);
    k_recon_mfma<<<NRB, 512, 0, stream>>>(hfrag, Wd2, bd2, x, out, reconpart);
    k_final     <<<1, 256, 0, stream>>>(reconpart, vqpart, idxp, out, obase);
}